// Round 1
// baseline (130.217 us; speedup 1.0000x reference)
//
#include <hip/hip_runtime.h>
#include <math.h>

typedef __attribute__((ext_vector_type(8))) _Float16 half8;
typedef __attribute__((ext_vector_type(4))) _Float16 half4;
typedef __attribute__((ext_vector_type(4))) float    f32x4;
typedef __attribute__((ext_vector_type(2))) float    f32x2;

#define TSTEPS 28
#define IDIM   28
#define HDIM   128
#define NKC    5       // K chunks of 32: 160 = 128 (h) + 28 (x) + bias(1) + 3 pad
#define TILE_B 32      // two pipelined row-groups of 16
#define CDIM   10

#if __has_builtin(__builtin_amdgcn_exp2f)
#define EXP2F(x) __builtin_amdgcn_exp2f(x)
#else
#define EXP2F(x) exp2f(x)
#endif
#if __has_builtin(__builtin_amdgcn_rcpf)
#define RCPF(x) __builtin_amdgcn_rcpf(x)
#else
#define RCPF(x) (1.0f / (x))
#endif

#define NLOG2E (-1.44269504f)
#define P2LOG2E (2.88539008f)

// P[kc][t][w][lane][j] (f16): B-fragment order for mfma_f32_16x16x32_f16.
// Activation scales folded (i,f,o x -log2e; g x 2log2e). Bias row at k=156
// (pairs with constant 1.0 in A column 156). k=157..159 zero.
__global__ __launch_bounds__(256) void pack_w(const float* __restrict__ Wih,
                                              const float* __restrict__ Whh,
                                              const float* __restrict__ bih,
                                              const float* __restrict__ bhh,
                                              _Float16* __restrict__ P) {
    int e = blockIdx.x * 256 + threadIdx.x;      // 5*4*8*64*8 = 81920
    if (e >= NKC * 4 * 8 * 64 * 8) return;
    int j  = e & 7;
    int ln = (e >> 3) & 63;
    int w  = (e >> 9) & 7;
    int t  = (e >> 12) & 3;
    int kc = e >> 14;
    int k  = kc * 32 + ((ln >> 4) << 3) + j;
    int u  = w * 16 + (ln & 15);
    int g  = t * HDIM + u;
    float v = 0.f;
    if (k < HDIM)                   v = Whh[g * HDIM + k];
    else if (k < HDIM + IDIM)       v = Wih[g * IDIM + (k - HDIM)];
    else if (k == HDIM + IDIM)      v = bih[g] + bhh[g];   // bias row
    float sc = (t == 2) ? P2LOG2E : NLOG2E;
    P[e] = (_Float16)(v * sc);
}

// Two row-groups (A = rows 0..15, B = rows 16..31) pipelined a half-step
// apart: each barrier interval contains one group's 16 h-MFMAs AND the other
// group's activation (trans-heavy) + 4 kc4 MFMAs, so the MFMA, VALU and
// transcendental pipes are all fed in every interval instead of bursting.
// 1 block/CU (grid 256) -> register budget allows ALL B-frags in registers
// (no Plds). h-frags single-buffered per group (read/write alternate phases).
__global__ __launch_bounds__(512, 2) void lstm_kernel(
    const float* __restrict__ x,          // [B][28][28] fp32
    const _Float16* __restrict__ P,       // packed weights, 160 KB
    const float* __restrict__ Wfc,        // [10][128]
    const float* __restrict__ b_fc,       // [10]
    float* __restrict__ out)              // [B][10]
{
    __shared__ __align__(16) _Float16 frag[2][NKC][64][8];     // 10 KB
    __shared__ __align__(16) float hplain[TILE_B][HDIM + 4];   // 16.9 KB

    const int tid = threadIdx.x;
    const int l   = tid & 63;
    const int w   = tid >> 6;                  // wave 0..7
    const int b0  = blockIdx.x * TILE_B;

    // ---- all B-frags in registers: h-part kc0..3 (64 regs) + kc4 (16) ----
    half8 breg[4][4];
    half8 breg4[4];
    {
        const half8* Pp = (const half8*)P;
        #pragma unroll
        for (int kc = 0; kc < 4; ++kc)
            #pragma unroll
            for (int t4 = 0; t4 < 4; ++t4)
                breg[t4][kc] = Pp[((kc * 4 + t4) * 8 + w) * 64 + l];
        #pragma unroll
        for (int t4 = 0; t4 < 4; ++t4)
            breg4[t4] = Pp[((4 * 4 + t4) * 8 + w) * 64 + l];
    }

    // ---- init LDS: zero h-chunks of both groups; bias-1.0 column both ----
    {
        float4 z = {0.f, 0.f, 0.f, 0.f};
        if (tid < 256) {                       // chunks 0..3: 256 float4 each
            ((float4*)frag)[tid] = z;          // group A (byte 0..4095)
            ((float4*)frag)[320 + tid] = z;    // group B (byte 5120..9215)
        }
    }
    if (tid < 32) {   // k=156 -> 1.0, k=157..159 -> 0 (slots 48..63, j=4..7)
        int g = tid >> 4, i = tid & 15;
        half4 onev = {(_Float16)1.f, (_Float16)0.f, (_Float16)0.f, (_Float16)0.f};
        *(half4*)&frag[g][4][48 + i][4] = onev;
    }

    // ---- x loaders: 14 lanes per wave (112 total) -> no wave skew ----
    const bool xact = (l < 14);
    const int xid   = w * 14 + l;              // 0..111
    const int xrow  = xid / 7, xg = xid % 7;
    const int xslot = xrow + 16 * (xg >> 1);
    const int xoff  = (xg & 1) * 4;
    const float4* xsA = (const float4*)(x + (size_t)(b0 + xrow) * (TSTEPS * IDIM));
    const float4* xsB = (const float4*)(x + (size_t)(b0 + 16 + xrow) * (TSTEPS * IDIM));
    float4 xh;
    if (xact) {
        float4 xa0 = xsA[xg];                  // x_A(0)
        float4 xb0 = xsB[xg];                  // x_B(0)
        half4 ha = {(_Float16)xa0.x, (_Float16)xa0.y, (_Float16)xa0.z, (_Float16)xa0.w};
        half4 hb = {(_Float16)xb0.x, (_Float16)xb0.y, (_Float16)xb0.z, (_Float16)xb0.w};
        *(half4*)&frag[0][4][xslot][xoff] = ha;
        *(half4*)&frag[1][4][xslot][xoff] = hb;
        xh = xsA[7 + xg];                      // issue x_A(1)
    }

    f32x2 cA01 = {0.f, 0.f}, cA23 = {0.f, 0.f};
    f32x2 cB01 = {0.f, 0.f}, cB23 = {0.f, 0.f};
    const int u    = w * 16 + (l & 15);
    const int kc_h = w >> 1;                       // u>>5 (wave-uniform)
    const int quad = (2 * w + ((l >> 3) & 1)) & 3; // (u>>3)&3
    const int jh   = l & 7;                        // u&7
    const int mb   = (l >> 4) << 2;                // row base for this lane

    f32x4 acc_A[4], acc_B[4];

    // activation on one group's gates; write h-frags (+ hplain at last step)
    auto activation = [&](f32x4 (&g4)[4], f32x2 &c01, f32x2 &c23,
                          _Float16 (*fragA)[64][8], bool lastT, int rowbase) {
        float hv[4];
        #pragma unroll
        for (int rp = 0; rp < 2; ++rp) {
            const int r0 = rp * 2, r1 = r0 + 1;
            f32x2 Ei = {EXP2F(g4[0][r0]), EXP2F(g4[0][r1])};   // e^{-i}
            f32x2 Ef = {EXP2F(g4[1][r0]), EXP2F(g4[1][r1])};   // e^{-f}
            f32x2 Eg = {EXP2F(g4[2][r0]), EXP2F(g4[2][r1])};   // e^{2g}
            f32x2 Eo = {EXP2F(g4[3][r0]), EXP2F(g4[3][r1])};   // e^{-o}
            f32x2 one = {1.f, 1.f};
            f32x2 Di = Ei + one, Df = Ef + one, Dg = Eg + one, Do = Eo + one;
            f32x2 Pif = Di * Df, Pgo = Dg * Do;
            f32x2 Rif = {RCPF(Pif.x), RCPF(Pif.y)};
            f32x2 Rgo = {RCPF(Pgo.x), RCPF(Pgo.y)};
            f32x2 is = Rif * Df, fs = Rif * Di;
            f32x2 gt = one - 2.f * (Rgo * Do);
            f32x2 os = Rgo * Dg;
            f32x2 cstp = rp ? c23 : c01;
            f32x2 c = fs * cstp + is * gt;
            if (rp) c23 = c; else c01 = c;
            f32x2 Etc = {EXP2F(c.x * P2LOG2E), EXP2F(c.y * P2LOG2E)};
            f32x2 Dtc = Etc + one;
            f32x2 Rtc = {RCPF(Dtc.x), RCPF(Dtc.y)};
            f32x2 tc = one - 2.f * Rtc;
            f32x2 h2 = os * tc;
            hv[r0] = h2.x; hv[r1] = h2.y;
        }
        #pragma unroll
        for (int r = 0; r < 4; ++r) {
            fragA[kc_h][mb + r + 16 * quad][jh] = (_Float16)hv[r];
            if (lastT) hplain[rowbase + mb + r][u] = hv[r];
        }
    };

    // one barrier interval: h-MFMAs for group M; act + kc4 for group A
    auto run_phase = [&](f32x4 (&accM)[4], _Float16 (*fragM)[64][8],
                         f32x4 (&accA)[4], _Float16 (*fragA)[64][8],
                         f32x2 &c01, f32x2 &c23, int rowbase,
                         bool doAct, bool doKc4, bool lastT) {
        half8 a[4];
        #pragma unroll
        for (int kc = 0; kc < 4; ++kc)
            a[kc] = *(const half8*)&fragM[kc][l][0];
        half8 a4;
        if (doKc4) a4 = *(const half8*)&fragA[4][l][0];
        #pragma unroll
        for (int t4 = 0; t4 < 4; ++t4)
            #pragma unroll
            for (int kc = 0; kc < 4; ++kc)
                accM[t4] = __builtin_amdgcn_mfma_f32_16x16x32_f16(a[kc], breg[t4][kc], accM[t4], 0, 0, 0);
        if (doAct) activation(accA, c01, c23, fragA, lastT, rowbase);
        if (doKc4) {
            #pragma unroll
            for (int t4 = 0; t4 < 4; ++t4) { f32x4 z = {0.f, 0.f, 0.f, 0.f}; accA[t4] = z; }
            #pragma unroll
            for (int t4 = 0; t4 < 4; ++t4)
                accA[t4] = __builtin_amdgcn_mfma_f32_16x16x32_f16(a4, breg4[t4], accA[t4], 0, 0, 0);
        }
    };

    __syncthreads();

    // prologue: acc_A = kc4_A(0)  (x_A(0) + bias)
    {
        half8 aA4 = *(const half8*)&frag[0][4][l][0];
        #pragma unroll
        for (int t4 = 0; t4 < 4; ++t4) { f32x4 z = {0.f, 0.f, 0.f, 0.f}; acc_A[t4] = z; }
        #pragma unroll
        for (int t4 = 0; t4 < 4; ++t4)
            acc_A[t4] = __builtin_amdgcn_mfma_f32_16x16x32_f16(aA4, breg4[t4], acc_A[t4], 0, 0, 0);
    }
    __syncthreads();   // separates kc4_A(0) read from s=0's x_A(1) commit

    for (int t = 0; t < TSTEPS; ++t) {
        const bool more = (t + 1 < TSTEPS);

        // even phase: h-MFMA_A(t)  ||  act_B(t-1) + kc4_B(t)
        if (xact && more) {                    // commit x_A(t+1)
            half4 hc = {(_Float16)xh.x, (_Float16)xh.y, (_Float16)xh.z, (_Float16)xh.w};
            *(half4*)&frag[0][4][xslot][xoff] = hc;
        }
        run_phase(acc_A, frag[0], acc_B, frag[1], cB01, cB23, 16,
                  t > 0, true, false);
        if (xact && more) xh = xsB[(t + 1) * 7 + xg];   // issue x_B(t+1)
        __syncthreads();

        // odd phase: h-MFMA_B(t)  ||  act_A(t) + kc4_A(t+1)
        if (xact && more) {                    // commit x_B(t+1)
            half4 hc = {(_Float16)xh.x, (_Float16)xh.y, (_Float16)xh.z, (_Float16)xh.w};
            *(half4*)&frag[1][4][xslot][xoff] = hc;
        }
        run_phase(acc_B, frag[1], acc_A, frag[0], cA01, cA23, 0,
                  true, more, !more);
        if (xact && t + 2 < TSTEPS) xh = xsA[(t + 2) * 7 + xg];  // issue x_A(t+2)
        __syncthreads();
    }

    // final act_B(27) -> hplain rows 16..31
    activation(acc_B, cB01, cB23, frag[1], true, 16);
    __syncthreads();

    // ---- FC + ReLU epilogue ----
    if (tid < TILE_B * CDIM) {
        int row = tid / CDIM, c = tid % CDIM;
        const float4* hv4 = (const float4*)&hplain[row][0];
        const float4* wf  = (const float4*)(Wfc + c * HDIM);
        float s = b_fc[c];
        #pragma unroll
        for (int q = 0; q < 32; ++q) {
            float4 a4 = hv4[q], b4 = wf[q];
            s += a4.x * b4.x + a4.y * b4.y + a4.z * b4.z + a4.w * b4.w;
        }
        out[(size_t)(b0 + row) * CDIM + c] = fmaxf(s, 0.f);
    }
}

extern "C" void kernel_launch(void* const* d_in, const int* in_sizes, int n_in,
                              void* d_out, int out_size, void* d_ws, size_t ws_size,
                              hipStream_t stream) {
    const float* x   = (const float*)d_in[0];
    const float* Wih = (const float*)d_in[1];
    const float* Whh = (const float*)d_in[2];
    const float* bih = (const float*)d_in[3];
    const float* bhh = (const float*)d_in[4];
    const float* Wfc = (const float*)d_in[5];
    const float* bfc = (const float*)d_in[6];
    float* out = (float*)d_out;
    _Float16* P = (_Float16*)d_ws;     // 160 KB packed weights

    hipLaunchKernelGGL(pack_w, dim3(320), dim3(256), 0, stream, Wih, Whh, bih, bhh, P);
    hipLaunchKernelGGL(lstm_kernel, dim3(8192 / TILE_B), dim3(512), 0, stream,
                       x, P, Wfc, bfc, out);
}

// Round 2
// 128.897 us; speedup vs baseline: 1.0102x; 1.0102x over previous
//
#include <hip/hip_runtime.h>
#include <math.h>

typedef __attribute__((ext_vector_type(8))) _Float16 half8;
typedef __attribute__((ext_vector_type(4))) _Float16 half4;
typedef __attribute__((ext_vector_type(4))) float    f32x4;
typedef __attribute__((ext_vector_type(2))) float    f32x2;

#define TSTEPS 28
#define IDIM   28
#define HDIM   128
#define NKC    5       // K chunks of 32: 160 = 128 (h) + 28 (x) + bias(1) + 3 pad
#define TILE_B 32      // two pipelined row-groups of 16
#define CDIM   10

#if __has_builtin(__builtin_amdgcn_exp2f)
#define EXP2F(x) __builtin_amdgcn_exp2f(x)
#else
#define EXP2F(x) exp2f(x)
#endif
#if __has_builtin(__builtin_amdgcn_rcpf)
#define RCPF(x) __builtin_amdgcn_rcpf(x)
#else
#define RCPF(x) (1.0f / (x))
#endif
#if __has_builtin(__builtin_amdgcn_sched_group_barrier)
#define SGB(m,n) __builtin_amdgcn_sched_group_barrier((m),(n),0)
#else
#define SGB(m,n)
#endif

#define NLOG2E (-1.44269504f)
#define P2LOG2E (2.88539008f)

#define MFMA16(a,b,c) __builtin_amdgcn_mfma_f32_16x16x32_f16((a),(b),(c),0,0,0)

// Pinned per-phase pipeline: 5 ds_read | {TRANS 8, VALU 12, MFMA 4} x4 | MFMA 8.
// Act (register-only, independent of this phase's MFMAs) fills ds_read latency
// and MFMA-pipe occupancy; one wave feeds MFMA + VALU + TRANS concurrently.
#define SGB_PIPE_FULL() do {            \
    SGB(0x100, 5);                      \
    SGB(0x400, 8); SGB(0x002, 12);      \
    SGB(0x008, 4);                      \
    SGB(0x400, 8); SGB(0x002, 12);      \
    SGB(0x008, 4);                      \
    SGB(0x400, 8); SGB(0x002, 12);      \
    SGB(0x008, 4);                      \
    SGB(0x400, 8); SGB(0x002, 12);      \
    SGB(0x008, 4);                      \
    SGB(0x008, 4);                      \
} while (0)

// P[kc][t][w][lane][j] (f16): B-fragment order for mfma_f32_16x16x32_f16.
// Activation scales folded (i,f,o x -log2e; g x 2log2e). Bias row at k=156
// (pairs with constant 1.0 in A column 156). k=157..159 zero.
__global__ __launch_bounds__(256) void pack_w(const float* __restrict__ Wih,
                                              const float* __restrict__ Whh,
                                              const float* __restrict__ bih,
                                              const float* __restrict__ bhh,
                                              _Float16* __restrict__ P) {
    int e = blockIdx.x * 256 + threadIdx.x;      // 5*4*8*64*8 = 81920
    if (e >= NKC * 4 * 8 * 64 * 8) return;
    int j  = e & 7;
    int ln = (e >> 3) & 63;
    int w  = (e >> 9) & 7;
    int t  = (e >> 12) & 3;
    int kc = e >> 14;
    int k  = kc * 32 + ((ln >> 4) << 3) + j;
    int u  = w * 16 + (ln & 15);
    int g  = t * HDIM + u;
    float v = 0.f;
    if (k < HDIM)                   v = Whh[g * HDIM + k];
    else if (k < HDIM + IDIM)       v = Wih[g * IDIM + (k - HDIM)];
    else if (k == HDIM + IDIM)      v = bih[g] + bhh[g];   // bias row
    float sc = (t == 2) ? P2LOG2E : NLOG2E;
    P[e] = (_Float16)(v * sc);
}

__global__ __launch_bounds__(512, 2) void lstm_kernel(
    const float* __restrict__ x,          // [B][28][28] fp32
    const _Float16* __restrict__ P,       // packed weights, 160 KB
    const float* __restrict__ Wfc,        // [10][128]
    const float* __restrict__ b_fc,       // [10]
    float* __restrict__ out)              // [B][10]
{
    __shared__ __align__(16) _Float16 frag[2][NKC][64][8];     // 10 KB
    __shared__ __align__(16) float hplain[TILE_B][HDIM + 4];   // 16.9 KB

    const int tid = threadIdx.x;
    const int l   = tid & 63;
    const int w   = tid >> 6;                  // wave 0..7
    const int b0  = blockIdx.x * TILE_B;

    // ---- all B-frags in registers: h-part kc0..3 (64 regs) + kc4 (16) ----
    half8 breg[4][4];
    half8 breg4[4];
    {
        const half8* Pp = (const half8*)P;
        #pragma unroll
        for (int kc = 0; kc < 4; ++kc)
            #pragma unroll
            for (int t4 = 0; t4 < 4; ++t4)
                breg[t4][kc] = Pp[((kc * 4 + t4) * 8 + w) * 64 + l];
        #pragma unroll
        for (int t4 = 0; t4 < 4; ++t4)
            breg4[t4] = Pp[((4 * 4 + t4) * 8 + w) * 64 + l];
    }

    // ---- init LDS: zero h-chunks of both groups; bias-1.0 column both ----
    {
        float4 z = {0.f, 0.f, 0.f, 0.f};
        if (tid < 256) {                       // chunks 0..3: 256 float4 each
            ((float4*)frag)[tid] = z;          // group A
            ((float4*)frag)[320 + tid] = z;    // group B
        }
    }
    if (tid < 32) {   // k=156 -> 1.0, k=157..159 -> 0 (slots 48..63, j=4..7)
        int g = tid >> 4, i = tid & 15;
        half4 onev = {(_Float16)1.f, (_Float16)0.f, (_Float16)0.f, (_Float16)0.f};
        *(half4*)&frag[g][4][48 + i][4] = onev;
    }

    // ---- x loaders: 14 lanes per wave (112 total) -> no wave skew ----
    const bool xact = (l < 14);
    const int xid   = w * 14 + l;              // 0..111
    const int xrow  = xid / 7, xg = xid % 7;
    const int xslot = xrow + 16 * (xg >> 1);
    const int xoff  = (xg & 1) * 4;
    const float4* xsA = (const float4*)(x + (size_t)(b0 + xrow) * (TSTEPS * IDIM));
    const float4* xsB = (const float4*)(x + (size_t)(b0 + 16 + xrow) * (TSTEPS * IDIM));
    float4 xh;
    if (xact) {
        float4 xa0 = xsA[xg];                  // x_A(0)
        float4 xb0 = xsB[xg];                  // x_B(0)
        half4 ha = {(_Float16)xa0.x, (_Float16)xa0.y, (_Float16)xa0.z, (_Float16)xa0.w};
        half4 hb = {(_Float16)xb0.x, (_Float16)xb0.y, (_Float16)xb0.z, (_Float16)xb0.w};
        *(half4*)&frag[0][4][xslot][xoff] = ha;
        *(half4*)&frag[1][4][xslot][xoff] = hb;
        xh = xsA[7 + xg];                      // issue x_A(1)
    }

    f32x2 cA01 = {0.f, 0.f}, cA23 = {0.f, 0.f};
    f32x2 cB01 = {0.f, 0.f}, cB23 = {0.f, 0.f};
    const int u    = w * 16 + (l & 15);
    const int kc_h = w >> 1;                       // u>>5 (wave-uniform)
    const int quad = (2 * w + ((l >> 3) & 1)) & 3; // (u>>3)&3
    const int jh   = l & 7;                        // u&7
    const int mb   = (l >> 4) << 2;                // row base for this lane

    f32x4 acc_A[4], acc_B[4];
    const f32x4 zc = {0.f, 0.f, 0.f, 0.f};

    // one activation r-pair: gates g4 -> h pair; updates cell state cst
    auto act_rp = [&](f32x4 (&g4)[4], f32x2 &cst, int rp, float* hv) {
        const int r0 = rp * 2, r1 = r0 + 1;
        f32x2 Ei = {EXP2F(g4[0][r0]), EXP2F(g4[0][r1])};   // e^{-i}
        f32x2 Ef = {EXP2F(g4[1][r0]), EXP2F(g4[1][r1])};   // e^{-f}
        f32x2 Eg = {EXP2F(g4[2][r0]), EXP2F(g4[2][r1])};   // e^{2g}
        f32x2 Eo = {EXP2F(g4[3][r0]), EXP2F(g4[3][r1])};   // e^{-o}
        f32x2 one = {1.f, 1.f};
        f32x2 Di = Ei + one, Df = Ef + one, Dg = Eg + one, Do = Eo + one;
        f32x2 Pif = Di * Df, Pgo = Dg * Do;
        f32x2 Rif = {RCPF(Pif.x), RCPF(Pif.y)};
        f32x2 Rgo = {RCPF(Pgo.x), RCPF(Pgo.y)};
        f32x2 is = Rif * Df, fs = Rif * Di;
        f32x2 gt = one - 2.f * (Rgo * Do);
        f32x2 os = Rgo * Dg;
        f32x2 c = fs * cst + is * gt;
        cst = c;
        f32x2 Etc = {EXP2F(c.x * P2LOG2E), EXP2F(c.y * P2LOG2E)};
        f32x2 Dtc = Etc + one;
        f32x2 Rtc = {RCPF(Dtc.x), RCPF(Dtc.y)};
        f32x2 tc = one - 2.f * Rtc;
        f32x2 h2 = os * tc;
        hv[r0] = h2.x; hv[r1] = h2.y;
    };

    // full phase: h-MFMA for group M; act + kc4 reset for group A (interleaved)
    auto phase_full = [&](f32x4 (&accM)[4], _Float16 (*fragM)[64][8],
                          f32x4 (&accA)[4], _Float16 (*fragA)[64][8],
                          f32x2 &c01, f32x2 &c23) {
        half8 a0 = *(const half8*)&fragM[0][l][0];
        half8 a1 = *(const half8*)&fragM[1][l][0];
        half8 a2 = *(const half8*)&fragM[2][l][0];
        half8 a3 = *(const half8*)&fragM[3][l][0];
        half8 a4 = *(const half8*)&fragA[4][l][0];
        float hv[4];
        // t4 = 0
        accM[0] = MFMA16(a0, breg[0][0], accM[0]);
        accM[0] = MFMA16(a1, breg[0][1], accM[0]);
        accM[0] = MFMA16(a2, breg[0][2], accM[0]);
        accM[0] = MFMA16(a3, breg[0][3], accM[0]);
        act_rp(accA, c01, 0, hv);
        // t4 = 1
        accM[1] = MFMA16(a0, breg[1][0], accM[1]);
        accM[1] = MFMA16(a1, breg[1][1], accM[1]);
        accM[1] = MFMA16(a2, breg[1][2], accM[1]);
        accM[1] = MFMA16(a3, breg[1][3], accM[1]);
        act_rp(accA, c23, 1, hv);
        // t4 = 2
        accM[2] = MFMA16(a0, breg[2][0], accM[2]);
        accM[2] = MFMA16(a1, breg[2][1], accM[2]);
        accM[2] = MFMA16(a2, breg[2][2], accM[2]);
        accM[2] = MFMA16(a3, breg[2][3], accM[2]);
        #pragma unroll
        for (int r = 0; r < 4; ++r)
            fragA[kc_h][mb + r + 16 * quad][jh] = (_Float16)hv[r];
        // t4 = 3
        accM[3] = MFMA16(a0, breg[3][0], accM[3]);
        accM[3] = MFMA16(a1, breg[3][1], accM[3]);
        accM[3] = MFMA16(a2, breg[3][2], accM[3]);
        accM[3] = MFMA16(a3, breg[3][3], accM[3]);
        // kc4 reset for group A (x + bias of next consumed step)
        #pragma unroll
        for (int t4 = 0; t4 < 4; ++t4)
            accA[t4] = MFMA16(a4, breg4[t4], zc);
        SGB_PIPE_FULL();
    };

    __syncthreads();

    // prologue: acc_A = kc4_A(0)  (x_A(0) + bias)
    {
        half8 aA4 = *(const half8*)&frag[0][4][l][0];
        #pragma unroll
        for (int t4 = 0; t4 < 4; ++t4)
            acc_A[t4] = MFMA16(aA4, breg4[t4], zc);
    }
    __syncthreads();   // separates kc4_A(0) read from even(0)'s x_A(1) commit

    // ===== even phase 0: h-MFMA_A(0) + kc4_B(0)  (no act) =====
    if (xact) {        // commit x_A(1)
        half4 hc = {(_Float16)xh.x, (_Float16)xh.y, (_Float16)xh.z, (_Float16)xh.w};
        *(half4*)&frag[0][4][xslot][xoff] = hc;
    }
    {
        half8 a0 = *(const half8*)&frag[0][0][l][0];
        half8 a1 = *(const half8*)&frag[0][1][l][0];
        half8 a2 = *(const half8*)&frag[0][2][l][0];
        half8 a3 = *(const half8*)&frag[0][3][l][0];
        half8 a4 = *(const half8*)&frag[1][4][l][0];
        #pragma unroll
        for (int t4 = 0; t4 < 4; ++t4) {
            acc_A[t4] = MFMA16(a0, breg[t4][0], acc_A[t4]);
            acc_A[t4] = MFMA16(a1, breg[t4][1], acc_A[t4]);
            acc_A[t4] = MFMA16(a2, breg[t4][2], acc_A[t4]);
            acc_A[t4] = MFMA16(a3, breg[t4][3], acc_A[t4]);
        }
        #pragma unroll
        for (int t4 = 0; t4 < 4; ++t4)
            acc_B[t4] = MFMA16(a4, breg4[t4], zc);
    }
    if (xact) xh = xsB[7 + xg];                // issue x_B(1)
    __syncthreads();

    for (int t = 0; t < TSTEPS - 1; ++t) {
        // ---- odd phase t: h-MFMA_B(t) || act_A(t) + kc4_A(t+1) ----
        if (xact) {                            // commit x_B(t+1)
            half4 hc = {(_Float16)xh.x, (_Float16)xh.y, (_Float16)xh.z, (_Float16)xh.w};
            *(half4*)&frag[1][4][xslot][xoff] = hc;
        }
        phase_full(acc_B, frag[1], acc_A, frag[0], cA01, cA23);
        if (xact && t + 2 < TSTEPS) xh = xsA[(t + 2) * 7 + xg];  // issue x_A(t+2)
        __syncthreads();

        // ---- even phase t+1: h-MFMA_A(t+1) || act_B(t) + kc4_B(t+1) ----
        if (xact && t + 2 < TSTEPS) {          // commit x_A(t+2)
            half4 hc = {(_Float16)xh.x, (_Float16)xh.y, (_Float16)xh.z, (_Float16)xh.w};
            *(half4*)&frag[0][4][xslot][xoff] = hc;
        }
        phase_full(acc_A, frag[0], acc_B, frag[1], cB01, cB23);
        if (xact && t + 2 < TSTEPS) xh = xsB[(t + 2) * 7 + xg];  // issue x_B(t+2)
        __syncthreads();
    }

    // ===== last odd phase 27: h-MFMA_B(27) || act_A(27) -> hplain, no kc4 =====
    {
        half8 a0 = *(const half8*)&frag[1][0][l][0];
        half8 a1 = *(const half8*)&frag[1][1][l][0];
        half8 a2 = *(const half8*)&frag[1][2][l][0];
        half8 a3 = *(const half8*)&frag[1][3][l][0];
        float hv[4];
        acc_B[0] = MFMA16(a0, breg[0][0], acc_B[0]);
        acc_B[0] = MFMA16(a1, breg[0][1], acc_B[0]);
        acc_B[0] = MFMA16(a2, breg[0][2], acc_B[0]);
        acc_B[0] = MFMA16(a3, breg[0][3], acc_B[0]);
        act_rp(acc_A, cA01, 0, hv);
        acc_B[1] = MFMA16(a0, breg[1][0], acc_B[1]);
        acc_B[1] = MFMA16(a1, breg[1][1], acc_B[1]);
        acc_B[1] = MFMA16(a2, breg[1][2], acc_B[1]);
        acc_B[1] = MFMA16(a3, breg[1][3], acc_B[1]);
        act_rp(acc_A, cA23, 1, hv);
        acc_B[2] = MFMA16(a0, breg[2][0], acc_B[2]);
        acc_B[2] = MFMA16(a1, breg[2][1], acc_B[2]);
        acc_B[2] = MFMA16(a2, breg[2][2], acc_B[2]);
        acc_B[2] = MFMA16(a3, breg[2][3], acc_B[2]);
        #pragma unroll
        for (int r = 0; r < 4; ++r)
            hplain[mb + r][u] = hv[r];
        acc_B[3] = MFMA16(a0, breg[3][0], acc_B[3]);
        acc_B[3] = MFMA16(a1, breg[3][1], acc_B[3]);
        acc_B[3] = MFMA16(a2, breg[3][2], acc_B[3]);
        acc_B[3] = MFMA16(a3, breg[3][3], acc_B[3]);
    }

    // final act_B(27) -> hplain rows 16..31 (no frag write needed)
    {
        float hv[4];
        act_rp(acc_B, cB01, 0, hv);
        act_rp(acc_B, cB23, 1, hv);
        #pragma unroll
        for (int r = 0; r < 4; ++r)
            hplain[16 + mb + r][u] = hv[r];
    }
    __syncthreads();

    // ---- FC + ReLU epilogue ----
    if (tid < TILE_B * CDIM) {
        int row = tid / CDIM, c = tid % CDIM;
        const float4* hv4 = (const float4*)&hplain[row][0];
        const float4* wf  = (const float4*)(Wfc + c * HDIM);
        float s = b_fc[c];
        #pragma unroll
        for (int q = 0; q < 32; ++q) {
            float4 a4 = hv4[q], b4 = wf[q];
            s += a4.x * b4.x + a4.y * b4.y + a4.z * b4.z + a4.w * b4.w;
        }
        out[(size_t)(b0 + row) * CDIM + c] = fmaxf(s, 0.f);
    }
}

extern "C" void kernel_launch(void* const* d_in, const int* in_sizes, int n_in,
                              void* d_out, int out_size, void* d_ws, size_t ws_size,
                              hipStream_t stream) {
    const float* x   = (const float*)d_in[0];
    const float* Wih = (const float*)d_in[1];
    const float* Whh = (const float*)d_in[2];
    const float* bih = (const float*)d_in[3];
    const float* bhh = (const float*)d_in[4];
    const float* Wfc = (const float*)d_in[5];
    const float* bfc = (const float*)d_in[6];
    float* out = (float*)d_out;
    _Float16* P = (_Float16*)d_ws;     // 160 KB packed weights

    hipLaunchKernelGGL(pack_w, dim3(320), dim3(256), 0, stream, Wih, Whh, bih, bhh, P);
    hipLaunchKernelGGL(lstm_kernel, dim3(8192 / TILE_B), dim3(512), 0, stream,
                       x, P, Wfc, bfc, out);
}